// Round 10
// baseline (896.406 us; speedup 1.0000x reference)
//
#include <hip/hip_runtime.h>
#include <float.h>
#include <math.h>

#define BATCH 8
#define NPTS  2048
#define KNN   20
#define BN    (BATCH*NPTS)
#define SLOPE 0.2f
#define BNEPS 1e-5f

// ---------------- xx: per-point squared norm ----------------
__global__ void xx_kernel(const float* __restrict__ x, float* __restrict__ xx, int C) {
    int p = blockIdx.x * 256 + threadIdx.x;           // p in [0, BN)
    int b = p >> 11, n = p & (NPTS - 1);
    const float* xb = x + (size_t)b * C * NPTS;
    float s = 0.f;
    for (int c = 0; c < C; ++c) { float v = xb[(size_t)c * NPTS + n]; s = fmaf(v, v, s); }
    xx[p] = s;
}

// async global->LDS, 16B per lane (dest linear in lane order; proven knn6-8)
__device__ __forceinline__ void gload_lds16(const float* g, float* l) {
    __builtin_amdgcn_global_load_lds(
        (const __attribute__((address_space(1))) void*)g,
        (__attribute__((address_space(3))) void*)l, 16, 0, 0);
}

// 4x4 s-value tile (s = xx_c - 2*inner). Shared by phase 1 and phase 2 so the
// fp32 sequence is bitwise identical (required for the v <= T equality logic).
template<int C>
__device__ __forceinline__ void dist16(const float (*xrT)[32], const float (*xc)[128],
                                       const float* __restrict__ xxb, int j0,
                                       int ty4, int tx4,
                                       float4& d0, float4& d1, float4& d2, float4& d3) {
    float4 a0 = {0,0,0,0}, a1 = {0,0,0,0}, a2 = {0,0,0,0}, a3 = {0,0,0,0};
#pragma unroll 4
    for (int c = 0; c < C; ++c) {
        float4 rv = *(const float4*)&xrT[c][ty4];
        float4 cv = *(const float4*)&xc[c][tx4];
        a0.x = fmaf(rv.x, cv.x, a0.x); a0.y = fmaf(rv.x, cv.y, a0.y);
        a0.z = fmaf(rv.x, cv.z, a0.z); a0.w = fmaf(rv.x, cv.w, a0.w);
        a1.x = fmaf(rv.y, cv.x, a1.x); a1.y = fmaf(rv.y, cv.y, a1.y);
        a1.z = fmaf(rv.y, cv.z, a1.z); a1.w = fmaf(rv.y, cv.w, a1.w);
        a2.x = fmaf(rv.z, cv.x, a2.x); a2.y = fmaf(rv.z, cv.y, a2.y);
        a2.z = fmaf(rv.z, cv.z, a2.z); a2.w = fmaf(rv.z, cv.w, a2.w);
        a3.x = fmaf(rv.w, cv.x, a3.x); a3.y = fmaf(rv.w, cv.y, a3.y);
        a3.z = fmaf(rv.w, cv.z, a3.z); a3.w = fmaf(rv.w, cv.w, a3.w);
    }
    float4 xq = *(const float4*)&xxb[j0 + tx4];
    d0.x = xq.x - 2.f * a0.x; d0.y = xq.y - 2.f * a0.y;
    d0.z = xq.z - 2.f * a0.z; d0.w = xq.w - 2.f * a0.w;
    d1.x = xq.x - 2.f * a1.x; d1.y = xq.y - 2.f * a1.y;
    d1.z = xq.z - 2.f * a1.z; d1.w = xq.w - 2.f * a1.w;
    d2.x = xq.x - 2.f * a2.x; d2.y = xq.y - 2.f * a2.y;
    d2.z = xq.z - 2.f * a2.z; d2.w = xq.w - 2.f * a2.w;
    d3.x = xq.x - 2.f * a3.x; d3.y = xq.y - 2.f * a3.y;
    d3.z = xq.z - 2.f * a3.z; d3.w = xq.w - 2.f * a3.w;
}

// ---------------- kNN v9: value-only phase1 + exact index-recovery phase2 ---
// Phase 1: per-thread top-20 VALUES (2-VALU min/max bubble, 3x cheaper than
// the (v,i)-pair bubble that dominated knn2..8), thr filter (proven exact).
// Merge: per-row exact 20th value T. Phase 2: recompute s bitwise-identically,
// collect all (v,j) with v<=T (>=20, includes ties), emit by lex rank (v,i)
// == lax.top_k order. Deterministic despite LDS-atomic slot assignment.
template<int C>
__global__ __launch_bounds__(256, 2) void knn9_kernel(const float* __restrict__ x,
                                                      const float* __restrict__ xx,
                                                      int* __restrict__ idx) {
    constexpr int ROWS = 32, CHUNK = 128, NCH = NPTS / CHUNK;   // 16 chunks
    constexpr int NST  = (C * 32 + 255) / 256;                  // gload calls/thread
    constexpr int SLOTS = 32;

    __shared__ __align__(16) float xrT[C][32];
    __shared__ float Trow[ROWS];
    __shared__ __align__(16) union U {
        struct P1 { float xc[C][CHUNK]; float dt[ROWS][129]; float thrG[8][32]; } p1;
        struct PM { float mv[8][KNN][ROWS]; } pm;
        struct P2 { float xc[C][CHUNK]; float pv[ROWS][SLOTS + 1];
                    int pidx[ROWS][SLOTS + 1]; int cnt[ROWS]; } p2;
    } u;

    const int t  = threadIdx.x;
    const int b  = blockIdx.x >> 6;           // 64 tiles per batch
    const int r0 = (blockIdx.x & 63) * ROWS;
    const float* xb  = x  + (size_t)b * C * NPTS;
    const float* xxb = xx + (size_t)b * NPTS;
    const int ty = t >> 5, tx = t & 31;
    const int ty4 = ty * 4, tx4 = tx * 4;

    // ---- prologue: stage xrT, init thrG, async-load chunk 0 ----
    for (int f = t; f < ROWS * C; f += 256) {
        int r = f & 31, c = f >> 5;
        xrT[c][r] = xb[(size_t)c * NPTS + r0 + r];
    }
    u.p1.thrG[ty][tx] = FLT_MAX;
#pragma unroll
    for (int k = 0; k < NST; ++k) {
        int i = t + 256 * k;
        if (i < C * 32) {
            int c = i >> 5, j = (i & 31) * 4;
            gload_lds16(xb + (size_t)c * NPTS + j, &u.p1.xc[0][0] + (size_t)i * 4);
        }
    }

    float lv[KNN];
#pragma unroll
    for (int s = 0; s < KNN; ++s) lv[s] = FLT_MAX;

    __syncthreads();                          // drains vmcnt -> chunk 0 in xc

    // ---------------- phase 1: value-only top-20 ----------------
    for (int ch = 0; ch < NCH; ++ch) {
        int j0 = ch * CHUNK;
        float4 d0, d1, d2, d3;
        dist16<C>(xrT, u.p1.xc, xxb, j0, ty4, tx4, d0, d1, d2, d3);
        u.p1.dt[ty4 + 0][tx4 + 0] = d0.x; u.p1.dt[ty4 + 0][tx4 + 1] = d0.y;
        u.p1.dt[ty4 + 0][tx4 + 2] = d0.z; u.p1.dt[ty4 + 0][tx4 + 3] = d0.w;
        u.p1.dt[ty4 + 1][tx4 + 0] = d1.x; u.p1.dt[ty4 + 1][tx4 + 1] = d1.y;
        u.p1.dt[ty4 + 1][tx4 + 2] = d1.z; u.p1.dt[ty4 + 1][tx4 + 3] = d1.w;
        u.p1.dt[ty4 + 2][tx4 + 0] = d2.x; u.p1.dt[ty4 + 2][tx4 + 1] = d2.y;
        u.p1.dt[ty4 + 2][tx4 + 2] = d2.z; u.p1.dt[ty4 + 2][tx4 + 3] = d2.w;
        u.p1.dt[ty4 + 3][tx4 + 0] = d3.x; u.p1.dt[ty4 + 3][tx4 + 1] = d3.y;
        u.p1.dt[ty4 + 3][tx4 + 2] = d3.z; u.p1.dt[ty4 + 3][tx4 + 3] = d3.w;
        __syncthreads();                      // dt visible; xc reads complete

        if (ch + 1 < NCH) {
            int j0n = j0 + CHUNK;
#pragma unroll
            for (int k = 0; k < NST; ++k) {
                int i = t + 256 * k;
                if (i < C * 32) {
                    int c = i >> 5, j = (i & 31) * 4;
                    gload_lds16(xb + (size_t)c * NPTS + j0n + j,
                                &u.p1.xc[0][0] + (size_t)i * 4);
                }
            }
        }

        {
            int r = tx;
            float thr = u.p1.thrG[0][r];
#pragma unroll
            for (int g = 1; g < 8; ++g) thr = fminf(thr, u.p1.thrG[g][r]);
            const float* drow = &u.p1.dt[r][ty * 16];
#pragma unroll
            for (int m = 0; m < 16; ++m) {
                float v = drow[m];
                if (v < lv[KNN - 1] && v <= thr) {
                    lv[KNN - 1] = v;
#pragma unroll
                    for (int s = KNN - 1; s > 0; --s) {
                        float lo = fminf(lv[s - 1], lv[s]);
                        float hi = fmaxf(lv[s - 1], lv[s]);
                        lv[s - 1] = lo; lv[s] = hi;
                    }
                }
            }
        }
        u.p1.thrG[ty][tx] = lv[KNN - 1];
        __syncthreads();                      // drains gload -> next xc ready
    }

    // ---------------- merge: per-row exact 20th value T ----------------
#pragma unroll
    for (int s = 0; s < KNN; ++s) u.pm.mv[ty][s][tx] = lv[s];
    __syncthreads();
    if (t < ROWS) {
        float hv[8]; int pp[8];
#pragma unroll
        for (int g = 0; g < 8; ++g) { pp[g] = 0; hv[g] = u.pm.mv[g][0][t]; }
        float T = FLT_MAX;
        for (int o = 0; o < KNN; ++o) {
            float bv = hv[0]; int bg = 0;
#pragma unroll
            for (int g = 1; g < 8; ++g) if (hv[g] < bv) { bv = hv[g]; bg = g; }
            T = bv;
#pragma unroll
            for (int g = 0; g < 8; ++g)
                if (bg == g) { ++pp[g]; hv[g] = (pp[g] < KNN) ? u.pm.mv[g][pp[g]][t] : FLT_MAX; }
        }
        Trow[t] = T;
    }
    __syncthreads();                          // merge done; mv dead

    // ---------------- phase 2 init + stage chunk 0 ----------------
    for (int f = t; f < ROWS * (SLOTS + 1); f += 256)
        u.p2.pv[f / (SLOTS + 1)][f % (SLOTS + 1)] = FLT_MAX;
    if (t < ROWS) u.p2.cnt[t] = 0;
#pragma unroll
    for (int k = 0; k < NST; ++k) {
        int i = t + 256 * k;
        if (i < C * 32) {
            int c = i >> 5, j = (i & 31) * 4;
            gload_lds16(xb + (size_t)c * NPTS + j, &u.p2.xc[0][0] + (size_t)i * 4);
        }
    }
    float Tr0 = Trow[ty4 + 0], Tr1 = Trow[ty4 + 1];
    float Tr2 = Trow[ty4 + 2], Tr3 = Trow[ty4 + 3];
    __syncthreads();

    // ---------------- phase 2: exact recompute + collect (v,j) <= T ----------
    for (int ch = 0; ch < NCH; ++ch) {
        int j0 = ch * CHUNK;
        float4 d0, d1, d2, d3;
        dist16<C>(xrT, u.p2.xc, xxb, j0, ty4, tx4, d0, d1, d2, d3);
        __syncthreads();                      // xc reads complete

        if (ch + 1 < NCH) {
            int j0n = j0 + CHUNK;
#pragma unroll
            for (int k = 0; k < NST; ++k) {
                int i = t + 256 * k;
                if (i < C * 32) {
                    int c = i >> 5, j = (i & 31) * 4;
                    gload_lds16(xb + (size_t)c * NPTS + j0n + j,
                                &u.p2.xc[0][0] + (size_t)i * 4);
                }
            }
        }

#define KNN9_EMIT(vv, ri, Tri, cj)                                         \
        if ((vv) <= (Tri)) {                                               \
            int sl = atomicAdd(&u.p2.cnt[ty4 + (ri)], 1);                  \
            if (sl < SLOTS) {                                              \
                u.p2.pv[ty4 + (ri)][sl]   = (vv);                          \
                u.p2.pidx[ty4 + (ri)][sl] = j0 + tx4 + (cj);               \
            }                                                              \
        }
        KNN9_EMIT(d0.x, 0, Tr0, 0) KNN9_EMIT(d0.y, 0, Tr0, 1)
        KNN9_EMIT(d0.z, 0, Tr0, 2) KNN9_EMIT(d0.w, 0, Tr0, 3)
        KNN9_EMIT(d1.x, 1, Tr1, 0) KNN9_EMIT(d1.y, 1, Tr1, 1)
        KNN9_EMIT(d1.z, 1, Tr1, 2) KNN9_EMIT(d1.w, 1, Tr1, 3)
        KNN9_EMIT(d2.x, 2, Tr2, 0) KNN9_EMIT(d2.y, 2, Tr2, 1)
        KNN9_EMIT(d2.z, 2, Tr2, 2) KNN9_EMIT(d2.w, 2, Tr2, 3)
        KNN9_EMIT(d3.x, 3, Tr3, 0) KNN9_EMIT(d3.y, 3, Tr3, 1)
        KNN9_EMIT(d3.z, 3, Tr3, 2) KNN9_EMIT(d3.w, 3, Tr3, 3)
#undef KNN9_EMIT
        __syncthreads();                      // drains gload -> next xc ready
    }

    // ---------------- rank emit: lex (v,i) rank == lax.top_k order ----------
    {
        int r = tx;
        int* op = idx + (size_t)(b * NPTS + r0 + r) * KNN;
#pragma unroll
        for (int ss = 0; ss < 4; ++ss) {
            int s0 = ty4 + ss;
            float v0 = u.p2.pv[r][s0]; int i0 = u.p2.pidx[r][s0];
            if (v0 < FLT_MAX) {
                int rank = 0;
                for (int q = 0; q < SLOTS; ++q) {
                    float vq = u.p2.pv[r][q]; int iq = u.p2.pidx[r][q];
                    rank += (vq < v0 || (vq == v0 && iq < i0)) ? 1 : 0;
                }
                if (rank < KNN) op[rank] = i0;
            }
        }
    }
}

// ---------------- projection: y = x@Wtop, z = x@(Wbot-Wtop) ----------------
__global__ void proj_kernel(const float* __restrict__ x, const float* __restrict__ W,
                            float* __restrict__ y, float* __restrict__ z, int C, int Cout) {
    int p = blockIdx.x;
    int b = p >> 11, n = p & (NPTS - 1);
    int j = threadIdx.x;                      // j < Cout
    __shared__ float xc[64];
    if (j < C) xc[j] = x[(size_t)b * C * NPTS + (size_t)j * NPTS + n];
    __syncthreads();
    float sy = 0.f, sz = 0.f;
    for (int c = 0; c < C; ++c) {
        float xv = xc[c];
        float wt = W[c * Cout + j];
        float wb = W[(C + c) * Cout + j];
        sy = fmaf(xv, wt, sy);
        sz = fmaf(xv, wb - wt, sz);
    }
    y[(size_t)p * Cout + j] = sy;
    z[(size_t)p * Cout + j] = sz;
}

// ---------------- fused attention: one wave per point ----------------
template<int CO>
__global__ __launch_bounds__(256) void attn_kernel(const float* __restrict__ y,
                                                   const float* __restrict__ z,
                                                   const int* __restrict__ idx,
                                                   const float* __restrict__ a,
                                                   float* __restrict__ hout) {
    constexpr int NCH = CO / 64;
    constexpr int H   = CO / 4;
    int wv = threadIdx.x >> 6;
    int l  = threadIdx.x & 63;
    int p  = blockIdx.x * 4 + wv;             // b*N + n
    int b  = p >> 11;
    float hw[NCH][KNN], lg[NCH][KNN], zv[NCH], av[NCH];
#pragma unroll
    for (int q = 0; q < NCH; ++q) {
        int c = l + 64 * q;
        zv[q] = z[(size_t)p * CO + c];
        av[q] = a[(c & 3) * H + (c >> 2)];
    }
    const int* ip = idx + (size_t)p * KNN;
#pragma unroll
    for (int j = 0; j < KNN; ++j) {
        int m = ip[j];
        const float* yr = y + ((size_t)(b * NPTS) + m) * CO;
#pragma unroll
        for (int q = 0; q < NCH; ++q) {
            int c = l + 64 * q;
            float v = yr[c] + zv[q];
            hw[q][j] = v;
            float tt = v > 0.f ? v : v * SLOPE;
            float part = tt * av[q];
            part += __shfl_xor(part, 1);
            part += __shfl_xor(part, 2);
            lg[q][j] = part;
        }
    }
#pragma unroll
    for (int q = 0; q < NCH; ++q) {
        float mx = -FLT_MAX;
#pragma unroll
        for (int j = 0; j < KNN; ++j) mx = fmaxf(mx, lg[q][j]);
        float s = 0.f;
#pragma unroll
        for (int j = 0; j < KNN; ++j) { float e = expf(lg[q][j] - mx); lg[q][j] = e; s += e; }
        float inv = 1.f / s;
        float o = 0.f;
#pragma unroll
        for (int j = 0; j < KNN; ++j) o = fmaf(lg[q][j] * inv, hw[q][j], o);
        o = o > 0.f ? o : o * SLOPE;
        int c = l + 64 * q;
        hout[(size_t)p * CO + c] = o;
    }
}

// ---------------- BN stats, deterministic two-stage ----------------
__global__ void bnstatA_kernel(const float* __restrict__ h, float* __restrict__ part, int CO) {
    __shared__ float s1[256], s2[256];
    int g = blockIdx.x, t = threadIdx.x;
    int c = t & (CO - 1), sub = t / CO;
    int nsub = 256 / CO;
    const int ppb = BN / 64;                  // 256 points per block
    float a1 = 0.f, a2 = 0.f;
    for (int i = 0; i < ppb / nsub; ++i) {
        int p = g * ppb + sub + i * nsub;
        float v = h[(size_t)p * CO + c];
        a1 += v; a2 = fmaf(v, v, a2);
    }
    s1[t] = a1; s2[t] = a2;
    __syncthreads();
    if (sub == 0) {
        for (int k = 1; k < nsub; ++k) { a1 += s1[k * CO + c]; a2 += s2[k * CO + c]; }
        part[(size_t)g * CO + c]        = a1;
        part[(size_t)(64 + g) * CO + c] = a2;
    }
}

__global__ void bnstatB_kernel(const float* __restrict__ part, float* __restrict__ mu,
                               float* __restrict__ rstd, int CO) {
    int c = threadIdx.x;
    float s1 = 0.f, s2 = 0.f;
    for (int g = 0; g < 64; ++g) { s1 += part[(size_t)g * CO + c]; s2 += part[(size_t)(64 + g) * CO + c]; }
    float m   = s1 / (float)BN;
    float var = s2 / (float)BN - m * m;
    mu[c]   = m;
    rstd[c] = 1.f / sqrtf(var + BNEPS);
}

// ---------------- BN apply + leaky + transpose to (B,C,N) ----------------
template<int CO>
__global__ __launch_bounds__(256) void bnapply_kernel(const float* __restrict__ h,
                                                      const float* __restrict__ mu,
                                                      const float* __restrict__ rstd,
                                                      const float* __restrict__ gamma,
                                                      const float* __restrict__ beta,
                                                      float* __restrict__ xout) {
    __shared__ float tile[64][CO + 1];
    int g  = blockIdx.x;
    int p0 = g * 64;
    int b  = p0 >> 11, n0 = p0 & (NPTS - 1);
    int t  = threadIdx.x;
    for (int fi = t; fi < 64 * CO; fi += 256) {
        int pt = fi / CO, c = fi % CO;
        tile[pt][c] = h[(size_t)(p0 + pt) * CO + c];
    }
    __syncthreads();
    for (int fi = t; fi < 64 * CO; fi += 256) {
        int c = fi >> 6, nn = fi & 63;
        float v = tile[nn][c];
        v = (v - mu[c]) * rstd[c] * gamma[c] + beta[c];
        v = v > 0.f ? v : v * SLOPE;
        xout[((size_t)b * CO + c) * NPTS + n0 + nn] = v;
    }
}

// ---------------- host ----------------
static void run_layer(const float* xin, const float* W, const float* a,
                      const float* gm, const float* bt, float* xout, int C, int CO,
                      float* xx, int* idx, float* y, float* z, float* h,
                      float* part, float* mu, float* rstd, hipStream_t stream) {
    xx_kernel<<<BN / 256, 256, 0, stream>>>(xin, xx, C);
    if (C == 3)
        knn9_kernel<3><<<BATCH * 64, 256, 0, stream>>>(xin, xx, idx);
    else
        knn9_kernel<64><<<BATCH * 64, 256, 0, stream>>>(xin, xx, idx);
    proj_kernel<<<BN, CO, 0, stream>>>(xin, W, y, z, C, CO);
    if (CO == 64)
        attn_kernel<64><<<BN / 4, 256, 0, stream>>>(y, z, idx, a, h);
    else
        attn_kernel<128><<<BN / 4, 256, 0, stream>>>(y, z, idx, a, h);
    bnstatA_kernel<<<64, 256, 0, stream>>>(h, part, CO);
    bnstatB_kernel<<<1, CO, 0, stream>>>(part, mu, rstd, CO);
    if (CO == 64)
        bnapply_kernel<64><<<BN / 64, 256, 0, stream>>>(h, mu, rstd, gm, bt, xout);
    else
        bnapply_kernel<128><<<BN / 64, 256, 0, stream>>>(h, mu, rstd, gm, bt, xout);
}

extern "C" void kernel_launch(void* const* d_in, const int* in_sizes, int n_in,
                              void* d_out, int out_size, void* d_ws, size_t ws_size,
                              hipStream_t stream) {
    const float* x  = (const float*)d_in[0];
    const float* W[3]  = {(const float*)d_in[1], (const float*)d_in[5], (const float*)d_in[9]};
    const float* a[3]  = {(const float*)d_in[2], (const float*)d_in[6], (const float*)d_in[10]};
    const float* gm[3] = {(const float*)d_in[3], (const float*)d_in[7], (const float*)d_in[11]};
    const float* bt[3] = {(const float*)d_in[4], (const float*)d_in[8], (const float*)d_in[12]};

    char* base = (char*)d_ws;
    size_t off = 0;
    auto carve = [&](size_t bytes) -> void* {
        void* r = base + off;
        off = (off + bytes + 255) & ~(size_t)255;
        return r;
    };
    float* xx   = (float*)carve((size_t)BN * sizeof(float));
    int*   idx  = (int*)  carve((size_t)BN * KNN * sizeof(int));
    float* y    = (float*)carve((size_t)BN * 128 * sizeof(float));
    float* z    = (float*)carve((size_t)BN * 128 * sizeof(float));
    float* h    = (float*)carve((size_t)BN * 128 * sizeof(float));
    float* part = (float*)carve((size_t)128 * 128 * sizeof(float));
    float* mu   = (float*)carve(128 * sizeof(float));
    float* rstd = (float*)carve(128 * sizeof(float));
    float* x1   = (float*)carve((size_t)BATCH * 64 * NPTS * sizeof(float));
    float* x2   = (float*)carve((size_t)BATCH * 64 * NPTS * sizeof(float));
    float* out  = (float*)d_out;

    run_layer(x,  W[0], a[0], gm[0], bt[0], x1,  3,  64, xx, idx, y, z, h, part, mu, rstd, stream);
    run_layer(x1, W[1], a[1], gm[1], bt[1], x2,  64, 64, xx, idx, y, z, h, part, mu, rstd, stream);
    run_layer(x2, W[2], a[2], gm[2], bt[2], out, 64, 128, xx, idx, y, z, h, part, mu, rstd, stream);
}